// Round 3
// baseline (871.465 us; speedup 1.0000x reference)
//
#include <hip/hip_runtime.h>

#define NB 2048
#define SA 121
#define EMB_TOTAL (NB * 64 * SA)   // 15,859,712 floats

typedef short bf16x8 __attribute__((ext_vector_type(8)));
typedef float f32x4  __attribute__((ext_vector_type(4)));

__device__ __forceinline__ short f2bf(float f) {
    union { float f; unsigned u; } v; v.f = f;
    unsigned r = (v.u + 0x7fffu + ((v.u >> 16) & 1u)) >> 16;
    return (short)r;
}

#define MFMA(a, b, c) __builtin_amdgcn_mfma_f32_16x16x32_bf16((a), (b), (c), 0, 0, 0)

// Convert f32 weights -> zero-padded bf16 copies in workspace.
// ws layout (shorts): WQ[128*128] @0, WK @16384, WV @32768, WC[64*128] @49152
__global__ void convert_weights(const float* __restrict__ Wq, const float* __restrict__ Wk,
                                const float* __restrict__ Wv, const float* __restrict__ Wc,
                                short* __restrict__ ws) {
    int i = blockIdx.x * 256 + threadIdx.x;   // 0 .. 57343
    if (i < 49152) {
        int m = i / 16384;
        const float* W = (m == 0) ? Wq : ((m == 1) ? Wk : Wv);
        int j = i & 16383;
        int r = j >> 7, c = j & 127;
        float v = (r < SA && c < SA) ? W[r * SA + c] : 0.f;
        ws[i] = f2bf(v);
    } else {
        int j = i - 49152;                    // Wc is exactly [64][128]
        ws[i] = f2bf(Wc[j]);
    }
}

__launch_bounds__(256, 3)
__global__ void fused_kernel(const float* __restrict__ lidar, const float* __restrict__ hsi,
                             const float* __restrict__ bq, const float* __restrict__ bk,
                             const float* __restrict__ bv,
                             const float* __restrict__ Wr1, const float* __restrict__ br1,
                             const float* __restrict__ Wr2, const float* __restrict__ br2,
                             const float* __restrict__ bc,
                             const short* __restrict__ wsb, float* __restrict__ out) {
    // LDS (46.1 KB -> 3 blocks/CU)
    __shared__ __align__(16) short sC[64 * 136];   // q (bf16, [row ch][col s], stride 136)
    __shared__ __align__(16) short sD[128 * 72];   // k as [64][136], then G^T as [128][72]
    __shared__ __align__(16) short sE[64 * 72];    // P^T [g][h], then M [o][g]
    __shared__ float sR[260];                      // pooled[128], hidden[128], logits[4]

    const int tid  = threadIdx.x;
    const int b    = blockIdx.x;
    const int lane = tid & 63;
    const int wid  = tid >> 6;
    const int l16  = lane & 15;
    const int g16  = lane >> 4;

    const short* WQ = wsb;
    const short* WK = wsb + 16384;
    const short* WV = wsb + 32768;
    const short* WC = wsb + 49152;

    const float* gl = lidar + (size_t)b * 7744;   // [64][121] f32
    const float* gh = hsi   + (size_t)b * 7744;

    f32x4 eacc[8];
    #pragma unroll
    for (int n = 0; n < 8; ++n) eacc[n] = (f32x4){0.f, 0.f, 0.f, 0.f};

    #pragma unroll 1
    for (int dir = 0; dir < 2; ++dir) {
        const float* Xqk = dir ? gh : gl;
        const float* Xv  = dir ? gl : gh;
        const int colbase = dir ? 0 : 64;   // Wc cols: dir0->h_emb (64:), dir1->l_emb (:64)

        f32x4 qreg[8];   // q accumulators, kept live through phase C for the gate

        // ================= phase A: q,k projections (wave owns rows wid*16..+15) =====
        {
            const float* Xrow = Xqk + (wid * 16 + l16) * 121;
            bf16x8 afr[4];
            float rsum = 0.f;
            #pragma unroll
            for (int k0 = 0; k0 < 4; ++k0) {
                int c0 = k0 * 32 + g16 * 8;
                float f[8];
                if (c0 == 120) {                       // edge frag: cols 120..127
                    f[0] = Xrow[120];
                    #pragma unroll
                    for (int j = 1; j < 8; ++j) f[j] = 0.f;
                } else {
                    #pragma unroll
                    for (int j = 0; j < 8; ++j) f[j] = Xrow[c0 + j];
                }
                #pragma unroll
                for (int j = 0; j < 8; ++j) rsum += f[j];
                bf16x8 a;
                #pragma unroll
                for (int j = 0; j < 8; ++j) a[j] = f2bf(f[j]);
                afr[k0] = a;
            }
            f32x4 ka[8];
            #pragma unroll
            for (int n = 0; n < 8; ++n) { qreg[n] = (f32x4){0,0,0,0}; ka[n] = (f32x4){0,0,0,0}; }
            #pragma unroll
            for (int k0 = 0; k0 < 4; ++k0) {
                #pragma unroll
                for (int n = 0; n < 8; ++n) {
                    bf16x8 bq_ = *(const bf16x8*)&WQ[(n * 16 + l16) * 128 + k0 * 32 + g16 * 8];
                    bf16x8 bk_ = *(const bf16x8*)&WK[(n * 16 + l16) * 128 + k0 * 32 + g16 * 8];
                    qreg[n] = MFMA(afr[k0], bq_, qreg[n]);
                    ka[n]   = MFMA(afr[k0], bk_, ka[n]);
                }
            }
            #pragma unroll
            for (int n = 0; n < 8; ++n) {
                int sc_ = n * 16 + l16;
                float bqv = (sc_ < SA) ? bq[sc_] : 0.f;
                float bkv = (sc_ < SA) ? bk[sc_] : 0.f;
                #pragma unroll
                for (int r = 0; r < 4; ++r) {
                    int row = wid * 16 + g16 * 4 + r;
                    qreg[n][r] += bqv;
                    sC[row * 136 + sc_] = f2bf(qreg[n][r]);
                    sD[row * 136 + sc_] = f2bf(ka[n][r] + bkv);
                }
            }
            if (dir == 0) {   // lidar pooled row-sums -> sR[0..63]
                rsum += __shfl_xor(rsum, 16, 64);
                rsum += __shfl_xor(rsum, 32, 64);
                if (g16 == 0) sR[wid * 16 + l16] = rsum * (1.f / 121.f);
            }
        }
        __syncthreads();   // bar1

        // ================= phase B: scores = q @ k^T, softmax, P^T -> sE ==============
        {
            f32x4 sc4[4];
            #pragma unroll
            for (int n = 0; n < 4; ++n) sc4[n] = (f32x4){0,0,0,0};
            #pragma unroll
            for (int k0 = 0; k0 < 4; ++k0) {
                bf16x8 afr = *(const bf16x8*)&sC[(wid * 16 + l16) * 136 + k0 * 32 + g16 * 8];
                #pragma unroll
                for (int n = 0; n < 4; ++n) {
                    bf16x8 bfr = *(const bf16x8*)&sD[(n * 16 + l16) * 136 + k0 * 32 + g16 * 8];
                    sc4[n] = MFMA(afr, bfr, sc4[n]);
                }
            }
            #pragma unroll
            for (int r = 0; r < 4; ++r) {
                float mx = fmaxf(fmaxf(sc4[0][r], sc4[1][r]), fmaxf(sc4[2][r], sc4[3][r]));
                #pragma unroll
                for (int off = 1; off < 16; off <<= 1) mx = fmaxf(mx, __shfl_xor(mx, off, 64));
                float e0 = exp2f((sc4[0][r] - mx) * 1.44269504f);
                float e1 = exp2f((sc4[1][r] - mx) * 1.44269504f);
                float e2 = exp2f((sc4[2][r] - mx) * 1.44269504f);
                float e3 = exp2f((sc4[3][r] - mx) * 1.44269504f);
                float sum = e0 + e1 + e2 + e3;
                #pragma unroll
                for (int off = 1; off < 16; off <<= 1) sum += __shfl_xor(sum, off, 64);
                float inv = 1.f / sum;
                int crow = wid * 16 + g16 * 4 + r;      // h row
                sE[(0 * 16 + l16) * 72 + crow] = f2bf(e0 * inv);
                sE[(1 * 16 + l16) * 72 + crow] = f2bf(e1 * inv);
                sE[(2 * 16 + l16) * 72 + crow] = f2bf(e2 * inv);
                sE[(3 * 16 + l16) * 72 + crow] = f2bf(e3 * inv);
            }
        }
        __syncthreads();   // bar2

        // ====== phase C: v-proj + gate(q regs) -> G^T in sD; M = Wc_part @ P ==========
        {
            const float* Xrow = Xv + (wid * 16 + l16) * 121;
            bf16x8 afr[4];
            float rsum = 0.f;
            #pragma unroll
            for (int k0 = 0; k0 < 4; ++k0) {
                int c0 = k0 * 32 + g16 * 8;
                float f[8];
                if (c0 == 120) {
                    f[0] = Xrow[120];
                    #pragma unroll
                    for (int j = 1; j < 8; ++j) f[j] = 0.f;
                } else {
                    #pragma unroll
                    for (int j = 0; j < 8; ++j) f[j] = Xrow[c0 + j];
                }
                #pragma unroll
                for (int j = 0; j < 8; ++j) rsum += f[j];
                bf16x8 a;
                #pragma unroll
                for (int j = 0; j < 8; ++j) a[j] = f2bf(f[j]);
                afr[k0] = a;
            }
            f32x4 va[8];
            #pragma unroll
            for (int n = 0; n < 8; ++n) va[n] = (f32x4){0,0,0,0};
            #pragma unroll
            for (int k0 = 0; k0 < 4; ++k0) {
                #pragma unroll
                for (int n = 0; n < 8; ++n) {
                    bf16x8 bv_ = *(const bf16x8*)&WV[(n * 16 + l16) * 128 + k0 * 32 + g16 * 8];
                    va[n] = MFMA(afr[k0], bv_, va[n]);
                }
            }
            #pragma unroll
            for (int n = 0; n < 8; ++n) {
                int sc_ = n * 16 + l16;
                float bvv = (sc_ < SA) ? bv[sc_] : 0.f;
                #pragma unroll
                for (int r = 0; r < 4; ++r) {
                    int row = wid * 16 + g16 * 4 + r;
                    float g = (va[n][r] + bvv) * qreg[n][r];
                    sD[sc_ * 72 + row] = f2bf(g);        // G^T [s][c]
                }
            }
            if (dir == 0) {   // hsi pooled row-sums -> sR[64..127]
                rsum += __shfl_xor(rsum, 16, 64);
                rsum += __shfl_xor(rsum, 32, 64);
                if (g16 == 0) sR[64 + wid * 16 + l16] = rsum * (1.f / 121.f);
            }
            // M = Wc[:, colbase:colbase+64] @ P  (K = h, reads P^T rows g in sE)
            f32x4 macc[4];
            #pragma unroll
            for (int n = 0; n < 4; ++n) macc[n] = (f32x4){0,0,0,0};
            #pragma unroll
            for (int k0 = 0; k0 < 2; ++k0) {
                bf16x8 afrW = *(const bf16x8*)&WC[(wid * 16 + l16) * 128 + colbase + k0 * 32 + g16 * 8];
                #pragma unroll
                for (int n = 0; n < 4; ++n) {
                    bf16x8 bfr = *(const bf16x8*)&sE[(n * 16 + l16) * 72 + k0 * 32 + g16 * 8];
                    macc[n] = MFMA(afrW, bfr, macc[n]);
                }
            }
            __syncthreads();   // bar3: all P^T reads done before M overwrites sE
            #pragma unroll
            for (int n = 0; n < 4; ++n)
                #pragma unroll
                for (int r = 0; r < 4; ++r) {
                    int o = wid * 16 + g16 * 4 + r;
                    sE[o * 72 + n * 16 + l16] = f2bf(macc[n][r]);   // M [o][g]
                }
        }
        __syncthreads();   // bar4

        // ================= phase D: emb += M @ G ======================================
        #pragma unroll
        for (int k0 = 0; k0 < 2; ++k0) {
            bf16x8 afr = *(const bf16x8*)&sE[(wid * 16 + l16) * 72 + k0 * 32 + g16 * 8];
            #pragma unroll
            for (int n = 0; n < 8; ++n) {
                bf16x8 bfr = *(const bf16x8*)&sD[(n * 16 + l16) * 72 + k0 * 32 + g16 * 8];
                eacc[n] = MFMA(afr, bfr, eacc[n]);
            }
        }
        __syncthreads();   // bar5: protect sC/sD/sE for next dir
    }

    // ================= epilogue: emb + bc -> global ===================================
    float* eo = out + (size_t)b * 7744;
    {
        float bcv[4];
        #pragma unroll
        for (int r = 0; r < 4; ++r) bcv[r] = bc[wid * 16 + g16 * 4 + r];
        #pragma unroll
        for (int n = 0; n < 8; ++n) {
            int s = n * 16 + l16;
            if (s < SA) {
                #pragma unroll
                for (int r = 0; r < 4; ++r) {
                    int o = wid * 16 + g16 * 4 + r;
                    eo[o * 121 + s] = eacc[n][r] + bcv[r];
                }
            }
        }
    }

    // ================= router MLP (pooled sums already in sR[0..127]) =================
    if (tid < 128) {
        float a0 = 0.f, a1 = 0.f, a2 = 0.f, a3 = 0.f;
        for (int c = 0; c < 128; c += 4) {
            a0 += sR[c]     * Wr1[(c)     * 128 + tid];
            a1 += sR[c + 1] * Wr1[(c + 1) * 128 + tid];
            a2 += sR[c + 2] * Wr1[(c + 2) * 128 + tid];
            a3 += sR[c + 3] * Wr1[(c + 3) * 128 + tid];
        }
        sR[128 + tid] = fmaxf((a0 + a1) + (a2 + a3) + br1[tid], 0.f);
    }
    __syncthreads();
    if (tid < 4) {
        float a0 = 0.f, a1 = 0.f, a2 = 0.f, a3 = 0.f;
        for (int h = 0; h < 128; h += 4) {
            a0 += sR[128 + h]     * Wr2[(h)     * 4 + tid];
            a1 += sR[128 + h + 1] * Wr2[(h + 1) * 4 + tid];
            a2 += sR[128 + h + 2] * Wr2[(h + 2) * 4 + tid];
            a3 += sR[128 + h + 3] * Wr2[(h + 3) * 4 + tid];
        }
        sR[256 + tid] = (a0 + a1) + (a2 + a3) + br2[tid];
    }
    __syncthreads();
    if (tid < 4) {
        float m = fmaxf(fmaxf(sR[256], sR[257]), fmaxf(sR[258], sR[259]));
        float e = __expf(sR[256 + tid] - m);
        float s = 0.f;
        for (int p = 0; p < 4; ++p) s += __expf(sR[256 + p] - m);
        out[EMB_TOTAL + b * 4 + tid] = e / s;
    }
}

extern "C" void kernel_launch(void* const* d_in, const int* in_sizes, int n_in,
                              void* d_out, int out_size, void* d_ws, size_t ws_size,
                              hipStream_t stream) {
    const float* lidar = (const float*)d_in[0];
    const float* hsi   = (const float*)d_in[1];
    const float* Wq  = (const float*)d_in[2];  const float* bq  = (const float*)d_in[3];
    const float* Wk  = (const float*)d_in[4];  const float* bk  = (const float*)d_in[5];
    const float* Wv  = (const float*)d_in[6];  const float* bv  = (const float*)d_in[7];
    const float* Wr1 = (const float*)d_in[8];  const float* br1 = (const float*)d_in[9];
    const float* Wr2 = (const float*)d_in[10]; const float* br2 = (const float*)d_in[11];
    const float* Wc  = (const float*)d_in[12]; const float* bc  = (const float*)d_in[13];
    short* wsb = (short*)d_ws;
    float* out = (float*)d_out;

    hipLaunchKernelGGL(convert_weights, dim3(224), dim3(256), 0, stream, Wq, Wk, Wv, Wc, wsb);
    hipLaunchKernelGGL(fused_kernel, dim3(NB), dim3(256), 0, stream,
                       lidar, hsi, bq, bk, bv, Wr1, br1, Wr2, br2, bc, wsb, out);
}

// Round 4
// 673.134 us; speedup vs baseline: 1.2946x; 1.2946x over previous
//
#include <hip/hip_runtime.h>

#define NB 2048
#define SA 121
#define EMB_TOTAL (NB * 64 * SA)   // 15,859,712 floats

typedef short bf16x8 __attribute__((ext_vector_type(8)));
typedef float f32x4  __attribute__((ext_vector_type(4)));

__device__ __forceinline__ short f2bf(float f) {
    union { float f; unsigned u; } v; v.f = f;
    unsigned r = (v.u + 0x7fffu + ((v.u >> 16) & 1u)) >> 16;
    return (short)r;
}
__device__ __forceinline__ float bf2f(short s) {
    union { unsigned u; float f; } v; v.u = ((unsigned)(unsigned short)s) << 16;
    return v.f;
}

#define MFMA(a, b, c) __builtin_amdgcn_mfma_f32_16x16x32_bf16((a), (b), (c), 0, 0, 0)

// Convert f32 weights -> zero-padded bf16 copies in workspace.
// ws layout (shorts): WQ[128*128] @0, WK @16384, WV @32768, WC[64*128] @49152
__global__ void convert_weights(const float* __restrict__ Wq, const float* __restrict__ Wk,
                                const float* __restrict__ Wv, const float* __restrict__ Wc,
                                short* __restrict__ ws) {
    int i = blockIdx.x * 256 + threadIdx.x;   // 0 .. 57343
    if (i < 49152) {
        int m = i / 16384;
        const float* W = (m == 0) ? Wq : ((m == 1) ? Wk : Wv);
        int j = i & 16383;
        int r = j >> 7, c = j & 127;
        float v = (r < SA && c < SA) ? W[r * SA + c] : 0.f;
        ws[i] = f2bf(v);
    } else {
        int j = i - 49152;                    // Wc is exactly [64][128]
        ws[i] = f2bf(Wc[j]);
    }
}

__launch_bounds__(256, 3)
__global__ void fused_kernel(const float* __restrict__ lidar, const float* __restrict__ hsi,
                             const float* __restrict__ bq, const float* __restrict__ bk,
                             const float* __restrict__ bv,
                             const float* __restrict__ Wr1, const float* __restrict__ br1,
                             const float* __restrict__ Wr2, const float* __restrict__ br2,
                             const float* __restrict__ bc,
                             const short* __restrict__ wsb, float* __restrict__ out) {
    // LDS (46.1 KB -> 3 blocks/CU)
    __shared__ __align__(16) short sC[64 * 136];   // q (bf16, [ch][s], stride 136)
    __shared__ __align__(16) short sD[128 * 72];   // k as [64][136], then G^T as [128][72]
    __shared__ __align__(16) short sE[64 * 72];    // P^T [g][h], then M [o][g]
    __shared__ float sR[260];                      // pooled[128], hidden[128], logits[4]

    const int tid  = threadIdx.x;
    const int b    = blockIdx.x;
    const int lane = tid & 63;
    const int wid  = tid >> 6;
    const int l16  = lane & 15;
    const int g16  = lane >> 4;

    const short* WQ = wsb;
    const short* WK = wsb + 16384;
    const short* WV = wsb + 32768;
    const short* WC = wsb + 49152;

    const float* gl = lidar + (size_t)b * 7744;   // [64][121] f32
    const float* gh = hsi   + (size_t)b * 7744;

    f32x4 eacc[8];
    #pragma unroll
    for (int n = 0; n < 8; ++n) eacc[n] = (f32x4){0.f, 0.f, 0.f, 0.f};

    #pragma unroll 1
    for (int dir = 0; dir < 2; ++dir) {
        const float* Xqk = dir ? gh : gl;
        const float* Xv  = dir ? gl : gh;
        const int colbase = dir ? 0 : 64;   // Wc cols: dir0->h_emb (64:), dir1->l_emb (:64)

        // ================= phase A: q then k projections (wave owns rows wid*16..+15) ==
        {
            const float* Xrow = Xqk + (wid * 16 + l16) * 121;
            bf16x8 afr[4];
            float rsum = 0.f;
            #pragma unroll
            for (int k0 = 0; k0 < 4; ++k0) {
                int c0 = k0 * 32 + g16 * 8;
                float f[8];
                if (c0 == 120) {                       // edge frag: cols 120..127
                    f[0] = Xrow[120];
                    #pragma unroll
                    for (int j = 1; j < 8; ++j) f[j] = 0.f;
                } else {
                    #pragma unroll
                    for (int j = 0; j < 8; ++j) f[j] = Xrow[c0 + j];
                }
                #pragma unroll
                for (int j = 0; j < 8; ++j) rsum += f[j];
                bf16x8 a;
                #pragma unroll
                for (int j = 0; j < 8; ++j) a[j] = f2bf(f[j]);
                afr[k0] = a;
            }
            if (dir == 0) {   // lidar pooled row-sums -> sR[0..63]
                rsum += __shfl_xor(rsum, 16, 64);
                rsum += __shfl_xor(rsum, 32, 64);
                if (g16 == 0) sR[wid * 16 + l16] = rsum * (1.f / 121.f);
            }
            // ---- pass 1: q -> sC ----
            {
                f32x4 acc[8];
                #pragma unroll
                for (int n = 0; n < 8; ++n) acc[n] = (f32x4){0,0,0,0};
                #pragma unroll
                for (int k0 = 0; k0 < 4; ++k0)
                    #pragma unroll
                    for (int n = 0; n < 8; ++n) {
                        bf16x8 bfr = *(const bf16x8*)&WQ[(n * 16 + l16) * 128 + k0 * 32 + g16 * 8];
                        acc[n] = MFMA(afr[k0], bfr, acc[n]);
                    }
                #pragma unroll
                for (int n = 0; n < 8; ++n) {
                    int sc_ = n * 16 + l16;
                    float bb = (sc_ < SA) ? bq[sc_] : 0.f;
                    #pragma unroll
                    for (int r = 0; r < 4; ++r) {
                        int row = wid * 16 + g16 * 4 + r;
                        sC[row * 136 + sc_] = f2bf(acc[n][r] + bb);
                    }
                }
            }
            // ---- pass 2: k -> sD ----
            {
                f32x4 acc[8];
                #pragma unroll
                for (int n = 0; n < 8; ++n) acc[n] = (f32x4){0,0,0,0};
                #pragma unroll
                for (int k0 = 0; k0 < 4; ++k0)
                    #pragma unroll
                    for (int n = 0; n < 8; ++n) {
                        bf16x8 bfr = *(const bf16x8*)&WK[(n * 16 + l16) * 128 + k0 * 32 + g16 * 8];
                        acc[n] = MFMA(afr[k0], bfr, acc[n]);
                    }
                #pragma unroll
                for (int n = 0; n < 8; ++n) {
                    int sc_ = n * 16 + l16;
                    float bb = (sc_ < SA) ? bk[sc_] : 0.f;
                    #pragma unroll
                    for (int r = 0; r < 4; ++r) {
                        int row = wid * 16 + g16 * 4 + r;
                        sD[row * 136 + sc_] = f2bf(acc[n][r] + bb);
                    }
                }
            }
        }
        __syncthreads();   // bar1

        // ================= phase B: scores = q @ k^T, softmax, P^T -> sE ==============
        {
            f32x4 sc4[4];
            #pragma unroll
            for (int n = 0; n < 4; ++n) sc4[n] = (f32x4){0,0,0,0};
            #pragma unroll
            for (int k0 = 0; k0 < 4; ++k0) {
                bf16x8 afr = *(const bf16x8*)&sC[(wid * 16 + l16) * 136 + k0 * 32 + g16 * 8];
                #pragma unroll
                for (int n = 0; n < 4; ++n) {
                    bf16x8 bfr = *(const bf16x8*)&sD[(n * 16 + l16) * 136 + k0 * 32 + g16 * 8];
                    sc4[n] = MFMA(afr, bfr, sc4[n]);
                }
            }
            #pragma unroll
            for (int r = 0; r < 4; ++r) {
                float mx = fmaxf(fmaxf(sc4[0][r], sc4[1][r]), fmaxf(sc4[2][r], sc4[3][r]));
                #pragma unroll
                for (int off = 1; off < 16; off <<= 1) mx = fmaxf(mx, __shfl_xor(mx, off, 64));
                float e0 = exp2f((sc4[0][r] - mx) * 1.44269504f);
                float e1 = exp2f((sc4[1][r] - mx) * 1.44269504f);
                float e2 = exp2f((sc4[2][r] - mx) * 1.44269504f);
                float e3 = exp2f((sc4[3][r] - mx) * 1.44269504f);
                float sum = e0 + e1 + e2 + e3;
                #pragma unroll
                for (int off = 1; off < 16; off <<= 1) sum += __shfl_xor(sum, off, 64);
                float inv = 1.f / sum;
                int crow = wid * 16 + g16 * 4 + r;      // h row
                sE[(0 * 16 + l16) * 72 + crow] = f2bf(e0 * inv);
                sE[(1 * 16 + l16) * 72 + crow] = f2bf(e1 * inv);
                sE[(2 * 16 + l16) * 72 + crow] = f2bf(e2 * inv);
                sE[(3 * 16 + l16) * 72 + crow] = f2bf(e3 * inv);
            }
        }
        __syncthreads();   // bar2

        // ====== phase C: v-proj + gate(q from sC) -> G^T in sD; M = Wc_part @ P =======
        {
            const float* Xrow = Xv + (wid * 16 + l16) * 121;
            bf16x8 afr[4];
            float rsum = 0.f;
            #pragma unroll
            for (int k0 = 0; k0 < 4; ++k0) {
                int c0 = k0 * 32 + g16 * 8;
                float f[8];
                if (c0 == 120) {
                    f[0] = Xrow[120];
                    #pragma unroll
                    for (int j = 1; j < 8; ++j) f[j] = 0.f;
                } else {
                    #pragma unroll
                    for (int j = 0; j < 8; ++j) f[j] = Xrow[c0 + j];
                }
                #pragma unroll
                for (int j = 0; j < 8; ++j) rsum += f[j];
                bf16x8 a;
                #pragma unroll
                for (int j = 0; j < 8; ++j) a[j] = f2bf(f[j]);
                afr[k0] = a;
            }
            if (dir == 0) {   // hsi pooled row-sums -> sR[64..127]
                rsum += __shfl_xor(rsum, 16, 64);
                rsum += __shfl_xor(rsum, 32, 64);
                if (g16 == 0) sR[64 + wid * 16 + l16] = rsum * (1.f / 121.f);
            }
            f32x4 va[8];
            #pragma unroll
            for (int n = 0; n < 8; ++n) va[n] = (f32x4){0,0,0,0};
            #pragma unroll
            for (int k0 = 0; k0 < 4; ++k0)
                #pragma unroll
                for (int n = 0; n < 8; ++n) {
                    bf16x8 bfr = *(const bf16x8*)&WV[(n * 16 + l16) * 128 + k0 * 32 + g16 * 8];
                    va[n] = MFMA(afr[k0], bfr, va[n]);
                }
            #pragma unroll
            for (int n = 0; n < 8; ++n) {
                int sc_ = n * 16 + l16;
                float bvv = (sc_ < SA) ? bv[sc_] : 0.f;
                #pragma unroll
                for (int r = 0; r < 4; ++r) {
                    int row = wid * 16 + g16 * 4 + r;
                    float qv = bf2f(sC[row * 136 + sc_]);
                    sD[sc_ * 72 + row] = f2bf((va[n][r] + bvv) * qv);   // G^T [s][c]
                }
            }
            // M = Wc[:, colbase:colbase+64] @ P  (K = h, reads P^T rows g in sE)
            f32x4 macc[4];
            #pragma unroll
            for (int n = 0; n < 4; ++n) macc[n] = (f32x4){0,0,0,0};
            #pragma unroll
            for (int k0 = 0; k0 < 2; ++k0) {
                bf16x8 afrW = *(const bf16x8*)&WC[(wid * 16 + l16) * 128 + colbase + k0 * 32 + g16 * 8];
                #pragma unroll
                for (int n = 0; n < 4; ++n) {
                    bf16x8 bfr = *(const bf16x8*)&sE[(n * 16 + l16) * 72 + k0 * 32 + g16 * 8];
                    macc[n] = MFMA(afrW, bfr, macc[n]);
                }
            }
            __syncthreads();   // bar3: all P^T reads done before M overwrites sE
            #pragma unroll
            for (int n = 0; n < 4; ++n)
                #pragma unroll
                for (int r = 0; r < 4; ++r) {
                    int o = wid * 16 + g16 * 4 + r;
                    sE[o * 72 + n * 16 + l16] = f2bf(macc[n][r]);   // M [o][g]
                }
        }
        __syncthreads();   // bar4

        // ================= phase D: emb += M @ G ======================================
        #pragma unroll
        for (int k0 = 0; k0 < 2; ++k0) {
            bf16x8 afr = *(const bf16x8*)&sE[(wid * 16 + l16) * 72 + k0 * 32 + g16 * 8];
            #pragma unroll
            for (int n = 0; n < 8; ++n) {
                bf16x8 bfr = *(const bf16x8*)&sD[(n * 16 + l16) * 72 + k0 * 32 + g16 * 8];
                eacc[n] = MFMA(afr, bfr, eacc[n]);
            }
        }
        __syncthreads();   // bar5: protect sC/sD/sE for next dir
    }

    // ================= epilogue: emb + bc -> global ===================================
    float* eo = out + (size_t)b * 7744;
    {
        float bcv[4];
        #pragma unroll
        for (int r = 0; r < 4; ++r) bcv[r] = bc[wid * 16 + g16 * 4 + r];
        #pragma unroll
        for (int n = 0; n < 8; ++n) {
            int s = n * 16 + l16;
            if (s < SA) {
                #pragma unroll
                for (int r = 0; r < 4; ++r) {
                    int o = wid * 16 + g16 * 4 + r;
                    eo[o * 121 + s] = eacc[n][r] + bcv[r];
                }
            }
        }
    }

    // ================= router MLP (pooled sums already in sR[0..127]) =================
    if (tid < 128) {
        float a0 = 0.f, a1 = 0.f, a2 = 0.f, a3 = 0.f;
        for (int c = 0; c < 128; c += 4) {
            a0 += sR[c]     * Wr1[(c)     * 128 + tid];
            a1 += sR[c + 1] * Wr1[(c + 1) * 128 + tid];
            a2 += sR[c + 2] * Wr1[(c + 2) * 128 + tid];
            a3 += sR[c + 3] * Wr1[(c + 3) * 128 + tid];
        }
        sR[128 + tid] = fmaxf((a0 + a1) + (a2 + a3) + br1[tid], 0.f);
    }
    __syncthreads();
    if (tid < 4) {
        float a0 = 0.f, a1 = 0.f, a2 = 0.f, a3 = 0.f;
        for (int h = 0; h < 128; h += 4) {
            a0 += sR[128 + h]     * Wr2[(h)     * 4 + tid];
            a1 += sR[128 + h + 1] * Wr2[(h + 1) * 4 + tid];
            a2 += sR[128 + h + 2] * Wr2[(h + 2) * 4 + tid];
            a3 += sR[128 + h + 3] * Wr2[(h + 3) * 4 + tid];
        }
        sR[256 + tid] = (a0 + a1) + (a2 + a3) + br2[tid];
    }
    __syncthreads();
    if (tid < 4) {
        float m = fmaxf(fmaxf(sR[256], sR[257]), fmaxf(sR[258], sR[259]));
        float e = __expf(sR[256 + tid] - m);
        float s = 0.f;
        for (int p = 0; p < 4; ++p) s += __expf(sR[256 + p] - m);
        out[EMB_TOTAL + b * 4 + tid] = e / s;
    }
}

extern "C" void kernel_launch(void* const* d_in, const int* in_sizes, int n_in,
                              void* d_out, int out_size, void* d_ws, size_t ws_size,
                              hipStream_t stream) {
    const float* lidar = (const float*)d_in[0];
    const float* hsi   = (const float*)d_in[1];
    const float* Wq  = (const float*)d_in[2];  const float* bq  = (const float*)d_in[3];
    const float* Wk  = (const float*)d_in[4];  const float* bk  = (const float*)d_in[5];
    const float* Wv  = (const float*)d_in[6];  const float* bv  = (const float*)d_in[7];
    const float* Wr1 = (const float*)d_in[8];  const float* br1 = (const float*)d_in[9];
    const float* Wr2 = (const float*)d_in[10]; const float* br2 = (const float*)d_in[11];
    const float* Wc  = (const float*)d_in[12]; const float* bc  = (const float*)d_in[13];
    short* wsb = (short*)d_ws;
    float* out = (float*)d_out;

    hipLaunchKernelGGL(convert_weights, dim3(224), dim3(256), 0, stream, Wq, Wk, Wv, Wc, wsb);
    hipLaunchKernelGGL(fused_kernel, dim3(NB), dim3(256), 0, stream,
                       lidar, hsi, bq, bk, bv, Wr1, br1, Wr2, br2, bc, wsb, out);
}

// Round 5
// 250.700 us; speedup vs baseline: 3.4761x; 2.6850x over previous
//
#include <hip/hip_runtime.h>

#define NB 2048
#define SA 121
#define EMB_TOTAL (NB * 64 * SA)   // 15,859,712 floats

typedef short bf16x8 __attribute__((ext_vector_type(8)));
typedef float f32x4  __attribute__((ext_vector_type(4)));

__device__ __forceinline__ short f2bf(float f) {
    union { float f; unsigned u; } v; v.f = f;
    unsigned r = (v.u + 0x7fffu + ((v.u >> 16) & 1u)) >> 16;
    return (short)r;
}
__device__ __forceinline__ float bf2f(short s) {
    union { unsigned u; float f; } v; v.u = ((unsigned)(unsigned short)s) << 16;
    return v.f;
}

#define MFMA(a, b, c) __builtin_amdgcn_mfma_f32_16x16x32_bf16((a), (b), (c), 0, 0, 0)

// Convert f32 weights -> zero-padded bf16 copies in workspace.
// ws layout (shorts): WQ[128*128] @0, WK @16384, WV @32768, WC[64*128] @49152
__global__ void convert_weights(const float* __restrict__ Wq, const float* __restrict__ Wk,
                                const float* __restrict__ Wv, const float* __restrict__ Wc,
                                short* __restrict__ ws) {
    int i = blockIdx.x * 256 + threadIdx.x;   // 0 .. 57343
    if (i < 49152) {
        int m = i / 16384;
        const float* W = (m == 0) ? Wq : ((m == 1) ? Wk : Wv);
        int j = i & 16383;
        int r = j >> 7, c = j & 127;
        float v = (r < SA && c < SA) ? W[r * SA + c] : 0.f;
        ws[i] = f2bf(v);
    } else {
        int j = i - 49152;                    // Wc is exactly [64][128]
        ws[i] = f2bf(Wc[j]);
    }
}

__launch_bounds__(256, 2)
__global__ void fused_kernel(const float* __restrict__ lidar, const float* __restrict__ hsi,
                             const float* __restrict__ bq, const float* __restrict__ bk,
                             const float* __restrict__ bv,
                             const float* __restrict__ Wr1, const float* __restrict__ br1,
                             const float* __restrict__ Wr2, const float* __restrict__ br2,
                             const float* __restrict__ bc,
                             const short* __restrict__ wsb, float* __restrict__ out) {
    // LDS (46.1 KB -> up to 3 blocks/CU if VGPRs allow)
    __shared__ __align__(16) short sC[64 * 136];   // q (bf16, [ch][s], stride 136)
    __shared__ __align__(16) short sD[128 * 72];   // k as [64][136], then G^T as [128][72]
    __shared__ __align__(16) short sE[64 * 72];    // P^T [g][h], then M [o][g]
    __shared__ float sR[260];                      // pooled[128], hidden[128], logits[4]

    const int tid  = threadIdx.x;
    const int b    = blockIdx.x;
    const int lane = tid & 63;
    const int wid  = tid >> 6;
    const int l16  = lane & 15;
    const int g16  = lane >> 4;

    const short* WQ = wsb;
    const short* WK = wsb + 16384;
    const short* WV = wsb + 32768;
    const short* WC = wsb + 49152;

    const float* gl = lidar + (size_t)b * 7744;   // [64][121] f32
    const float* gh = hsi   + (size_t)b * 7744;

    f32x4 eacc[8];
    #pragma unroll
    for (int n = 0; n < 8; ++n) eacc[n] = (f32x4){0.f, 0.f, 0.f, 0.f};

    #pragma unroll 1
    for (int dir = 0; dir < 2; ++dir) {
        const float* Xqk = dir ? gh : gl;
        const float* Xv  = dir ? gl : gh;
        const int colbase = dir ? 0 : 64;   // Wc cols: dir0->h_emb (64:), dir1->l_emb (:64)

        // ================= phase A: q then k projections (wave owns rows wid*16..+15) ==
        {
            const float* Xrow = Xqk + (wid * 16 + l16) * 121;
            bf16x8 afr[4];
            float rsum = 0.f;
            #pragma unroll
            for (int k0 = 0; k0 < 4; ++k0) {
                int c0 = k0 * 32 + g16 * 8;
                bf16x8 a;
                if (c0 == 120) {                       // edge frag: cols 120..127
                    float x = Xrow[120];
                    rsum += x;
                    a[0] = f2bf(x);
                    #pragma unroll
                    for (int j = 1; j < 8; ++j) a[j] = 0;
                } else {
                    #pragma unroll
                    for (int j = 0; j < 8; ++j) {
                        float x = Xrow[c0 + j];
                        rsum += x;
                        a[j] = f2bf(x);
                    }
                }
                afr[k0] = a;
            }
            if (dir == 0) {   // lidar pooled row-sums -> sR[0..63]
                rsum += __shfl_xor(rsum, 16, 64);
                rsum += __shfl_xor(rsum, 32, 64);
                if (g16 == 0) sR[wid * 16 + l16] = rsum * (1.f / 121.f);
            }
            // q -> sC, then k -> sD; each in two n-halves (acc[4] to cap VGPR pressure)
            #pragma unroll 1
            for (int which = 0; which < 2; ++which) {
                const short* W    = which ? WK : WQ;
                const float* bias = which ? bk : bq;
                short* OUT        = which ? sD : sC;
                #pragma unroll 1
                for (int half = 0; half < 2; ++half) {
                    f32x4 acc[4];
                    #pragma unroll
                    for (int n4 = 0; n4 < 4; ++n4) acc[n4] = (f32x4){0, 0, 0, 0};
                    #pragma unroll
                    for (int k0 = 0; k0 < 4; ++k0)
                        #pragma unroll
                        for (int n4 = 0; n4 < 4; ++n4) {
                            int n = half * 4 + n4;
                            bf16x8 bfr = *(const bf16x8*)&W[(n * 16 + l16) * 128 + k0 * 32 + g16 * 8];
                            acc[n4] = MFMA(afr[k0], bfr, acc[n4]);
                        }
                    #pragma unroll
                    for (int n4 = 0; n4 < 4; ++n4) {
                        int sc_ = (half * 4 + n4) * 16 + l16;
                        float bb = (sc_ < SA) ? bias[sc_] : 0.f;
                        #pragma unroll
                        for (int r = 0; r < 4; ++r) {
                            int row = wid * 16 + g16 * 4 + r;
                            OUT[row * 136 + sc_] = f2bf(acc[n4][r] + bb);
                        }
                    }
                }
            }
        }
        __syncthreads();   // bar1

        // ================= phase B: scores = q @ k^T, softmax, P^T -> sE ==============
        {
            f32x4 sc4[4];
            #pragma unroll
            for (int n = 0; n < 4; ++n) sc4[n] = (f32x4){0,0,0,0};
            #pragma unroll
            for (int k0 = 0; k0 < 4; ++k0) {
                bf16x8 afr = *(const bf16x8*)&sC[(wid * 16 + l16) * 136 + k0 * 32 + g16 * 8];
                #pragma unroll
                for (int n = 0; n < 4; ++n) {
                    bf16x8 bfr = *(const bf16x8*)&sD[(n * 16 + l16) * 136 + k0 * 32 + g16 * 8];
                    sc4[n] = MFMA(afr, bfr, sc4[n]);
                }
            }
            #pragma unroll
            for (int r = 0; r < 4; ++r) {
                float mx = fmaxf(fmaxf(sc4[0][r], sc4[1][r]), fmaxf(sc4[2][r], sc4[3][r]));
                #pragma unroll
                for (int off = 1; off < 16; off <<= 1) mx = fmaxf(mx, __shfl_xor(mx, off, 64));
                float e0 = exp2f((sc4[0][r] - mx) * 1.44269504f);
                float e1 = exp2f((sc4[1][r] - mx) * 1.44269504f);
                float e2 = exp2f((sc4[2][r] - mx) * 1.44269504f);
                float e3 = exp2f((sc4[3][r] - mx) * 1.44269504f);
                float sum = e0 + e1 + e2 + e3;
                #pragma unroll
                for (int off = 1; off < 16; off <<= 1) sum += __shfl_xor(sum, off, 64);
                float inv = 1.f / sum;
                int crow = wid * 16 + g16 * 4 + r;      // h row
                sE[(0 * 16 + l16) * 72 + crow] = f2bf(e0 * inv);
                sE[(1 * 16 + l16) * 72 + crow] = f2bf(e1 * inv);
                sE[(2 * 16 + l16) * 72 + crow] = f2bf(e2 * inv);
                sE[(3 * 16 + l16) * 72 + crow] = f2bf(e3 * inv);
            }
        }
        __syncthreads();   // bar2

        // ====== phase C: v-proj + gate(q from sC) -> G^T in sD; M = Wc_part @ P =======
        {
            const float* Xrow = Xv + (wid * 16 + l16) * 121;
            bf16x8 afr[4];
            float rsum = 0.f;
            #pragma unroll
            for (int k0 = 0; k0 < 4; ++k0) {
                int c0 = k0 * 32 + g16 * 8;
                bf16x8 a;
                if (c0 == 120) {
                    float x = Xrow[120];
                    rsum += x;
                    a[0] = f2bf(x);
                    #pragma unroll
                    for (int j = 1; j < 8; ++j) a[j] = 0;
                } else {
                    #pragma unroll
                    for (int j = 0; j < 8; ++j) {
                        float x = Xrow[c0 + j];
                        rsum += x;
                        a[j] = f2bf(x);
                    }
                }
                afr[k0] = a;
            }
            if (dir == 0) {   // hsi pooled row-sums -> sR[64..127]
                rsum += __shfl_xor(rsum, 16, 64);
                rsum += __shfl_xor(rsum, 32, 64);
                if (g16 == 0) sR[64 + wid * 16 + l16] = rsum * (1.f / 121.f);
            }
            #pragma unroll 1
            for (int half = 0; half < 2; ++half) {
                f32x4 acc[4];
                #pragma unroll
                for (int n4 = 0; n4 < 4; ++n4) acc[n4] = (f32x4){0, 0, 0, 0};
                #pragma unroll
                for (int k0 = 0; k0 < 4; ++k0)
                    #pragma unroll
                    for (int n4 = 0; n4 < 4; ++n4) {
                        int n = half * 4 + n4;
                        bf16x8 bfr = *(const bf16x8*)&WV[(n * 16 + l16) * 128 + k0 * 32 + g16 * 8];
                        acc[n4] = MFMA(afr[k0], bfr, acc[n4]);
                    }
                #pragma unroll
                for (int n4 = 0; n4 < 4; ++n4) {
                    int sc_ = (half * 4 + n4) * 16 + l16;
                    float bvv = (sc_ < SA) ? bv[sc_] : 0.f;
                    #pragma unroll
                    for (int r = 0; r < 4; ++r) {
                        int row = wid * 16 + g16 * 4 + r;
                        float qv = bf2f(sC[row * 136 + sc_]);
                        sD[sc_ * 72 + row] = f2bf((acc[n4][r] + bvv) * qv);   // G^T [s][c]
                    }
                }
            }
            // M = Wc[:, colbase:colbase+64] @ P  (K = h, reads P^T rows g in sE)
            f32x4 macc[4];
            #pragma unroll
            for (int n = 0; n < 4; ++n) macc[n] = (f32x4){0,0,0,0};
            #pragma unroll
            for (int k0 = 0; k0 < 2; ++k0) {
                bf16x8 afrW = *(const bf16x8*)&WC[(wid * 16 + l16) * 128 + colbase + k0 * 32 + g16 * 8];
                #pragma unroll
                for (int n = 0; n < 4; ++n) {
                    bf16x8 bfr = *(const bf16x8*)&sE[(n * 16 + l16) * 72 + k0 * 32 + g16 * 8];
                    macc[n] = MFMA(afrW, bfr, macc[n]);
                }
            }
            __syncthreads();   // bar3: all P^T reads done before M overwrites sE
            #pragma unroll
            for (int n = 0; n < 4; ++n)
                #pragma unroll
                for (int r = 0; r < 4; ++r) {
                    int o = wid * 16 + g16 * 4 + r;
                    sE[o * 72 + n * 16 + l16] = f2bf(macc[n][r]);   // M [o][g]
                }
        }
        __syncthreads();   // bar4

        // ================= phase D: emb += M @ G ======================================
        #pragma unroll
        for (int k0 = 0; k0 < 2; ++k0) {
            bf16x8 afr = *(const bf16x8*)&sE[(wid * 16 + l16) * 72 + k0 * 32 + g16 * 8];
            #pragma unroll
            for (int n = 0; n < 8; ++n) {
                bf16x8 bfr = *(const bf16x8*)&sD[(n * 16 + l16) * 72 + k0 * 32 + g16 * 8];
                eacc[n] = MFMA(afr, bfr, eacc[n]);
            }
        }
        __syncthreads();   // bar5: protect sC/sD/sE for next dir
    }

    // ================= epilogue: emb + bc -> global ===================================
    float* eo = out + (size_t)b * 7744;
    {
        float bcv[4];
        #pragma unroll
        for (int r = 0; r < 4; ++r) bcv[r] = bc[wid * 16 + g16 * 4 + r];
        #pragma unroll
        for (int n = 0; n < 8; ++n) {
            int s = n * 16 + l16;
            if (s < SA) {
                #pragma unroll
                for (int r = 0; r < 4; ++r) {
                    int o = wid * 16 + g16 * 4 + r;
                    eo[o * 121 + s] = eacc[n][r] + bcv[r];
                }
            }
        }
    }

    // ================= router MLP (pooled sums already in sR[0..127]) =================
    if (tid < 128) {
        float a0 = 0.f, a1 = 0.f, a2 = 0.f, a3 = 0.f;
        for (int c = 0; c < 128; c += 4) {
            a0 += sR[c]     * Wr1[(c)     * 128 + tid];
            a1 += sR[c + 1] * Wr1[(c + 1) * 128 + tid];
            a2 += sR[c + 2] * Wr1[(c + 2) * 128 + tid];
            a3 += sR[c + 3] * Wr1[(c + 3) * 128 + tid];
        }
        sR[128 + tid] = fmaxf((a0 + a1) + (a2 + a3) + br1[tid], 0.f);
    }
    __syncthreads();
    if (tid < 4) {
        float a0 = 0.f, a1 = 0.f, a2 = 0.f, a3 = 0.f;
        for (int h = 0; h < 128; h += 4) {
            a0 += sR[128 + h]     * Wr2[(h)     * 4 + tid];
            a1 += sR[128 + h + 1] * Wr2[(h + 1) * 4 + tid];
            a2 += sR[128 + h + 2] * Wr2[(h + 2) * 4 + tid];
            a3 += sR[128 + h + 3] * Wr2[(h + 3) * 4 + tid];
        }
        sR[256 + tid] = (a0 + a1) + (a2 + a3) + br2[tid];
    }
    __syncthreads();
    if (tid < 4) {
        float m = fmaxf(fmaxf(sR[256], sR[257]), fmaxf(sR[258], sR[259]));
        float e = __expf(sR[256 + tid] - m);
        float s = 0.f;
        for (int p = 0; p < 4; ++p) s += __expf(sR[256 + p] - m);
        out[EMB_TOTAL + b * 4 + tid] = e / s;
    }
}

extern "C" void kernel_launch(void* const* d_in, const int* in_sizes, int n_in,
                              void* d_out, int out_size, void* d_ws, size_t ws_size,
                              hipStream_t stream) {
    const float* lidar = (const float*)d_in[0];
    const float* hsi   = (const float*)d_in[1];
    const float* Wq  = (const float*)d_in[2];  const float* bq  = (const float*)d_in[3];
    const float* Wk  = (const float*)d_in[4];  const float* bk  = (const float*)d_in[5];
    const float* Wv  = (const float*)d_in[6];  const float* bv  = (const float*)d_in[7];
    const float* Wr1 = (const float*)d_in[8];  const float* br1 = (const float*)d_in[9];
    const float* Wr2 = (const float*)d_in[10]; const float* br2 = (const float*)d_in[11];
    const float* Wc  = (const float*)d_in[12]; const float* bc  = (const float*)d_in[13];
    short* wsb = (short*)d_ws;
    float* out = (float*)d_out;

    hipLaunchKernelGGL(convert_weights, dim3(224), dim3(256), 0, stream, Wq, Wk, Wv, Wc, wsb);
    hipLaunchKernelGGL(fused_kernel, dim3(NB), dim3(256), 0, stream,
                       lidar, hsi, bq, bk, bv, Wr1, br1, Wr2, br2, bc, wsb, out);
}

// Round 6
// 114.524 us; speedup vs baseline: 7.6094x; 2.1891x over previous
//
#include <hip/hip_runtime.h>

#define NB 2048
#define SA 121
#define EMB_TOTAL (NB * 64 * SA)   // 15,859,712 floats

typedef short bf16x8 __attribute__((ext_vector_type(8)));
typedef float f32x4  __attribute__((ext_vector_type(4)));

__device__ __forceinline__ short f2bf(float f) {
    union { float f; unsigned u; } v; v.f = f;
    unsigned r = (v.u + 0x7fffu + ((v.u >> 16) & 1u)) >> 16;
    return (short)r;
}
__device__ __forceinline__ float bf2f(short s) {
    union { unsigned u; float f; } v; v.u = ((unsigned)(unsigned short)s) << 16;
    return v.f;
}

#define MFMA(a, b, c) __builtin_amdgcn_mfma_f32_16x16x32_bf16((a), (b), (c), 0, 0, 0)

// Convert f32 weights -> zero-padded bf16 copies in workspace.
// ws layout (shorts): WQ[128*128] @0, WK @16384, WV @32768, WC[64*128] @49152
__global__ void convert_weights(const float* __restrict__ Wq, const float* __restrict__ Wk,
                                const float* __restrict__ Wv, const float* __restrict__ Wc,
                                short* __restrict__ ws) {
    int i = blockIdx.x * 256 + threadIdx.x;   // 0 .. 57343
    if (i < 49152) {
        int m = i / 16384;
        const float* W = (m == 0) ? Wq : ((m == 1) ? Wk : Wv);
        int j = i & 16383;
        int r = j >> 7, c = j & 127;
        float v = (r < SA && c < SA) ? W[r * SA + c] : 0.f;
        ws[i] = f2bf(v);
    } else {
        int j = i - 49152;                    // Wc is exactly [64][128]
        ws[i] = f2bf(Wc[j]);
    }
}

__launch_bounds__(256, 2)
__global__ void fused_kernel(const float* __restrict__ lidar, const float* __restrict__ hsi,
                             const float* __restrict__ bq, const float* __restrict__ bk,
                             const float* __restrict__ bv,
                             const float* __restrict__ Wr1, const float* __restrict__ br1,
                             const float* __restrict__ Wr2, const float* __restrict__ br2,
                             const float* __restrict__ bc,
                             const short* __restrict__ wsb, float* __restrict__ out) {
    // LDS ~80.9 KB -> 2 blocks/CU (2*80912 <= 163840)
    __shared__ __align__(16) short sA[64 * 136];   // lidar bf16 [ch][s], stride 136
    __shared__ __align__(16) short sB[64 * 136];   // hsi
    __shared__ __align__(16) short sC[64 * 136];   // q
    __shared__ __align__(16) short sD[128 * 72];   // k as [64][136], then G^T as [128][72]
    __shared__ __align__(16) short sE[64 * 72];    // P^T [g][h], then M [o][g]
    __shared__ float sR[260];                      // pooled[128], hidden[128], logits[4]

    const int tid  = threadIdx.x;
    const int b    = blockIdx.x;
    const int lane = tid & 63;
    const int wid  = tid >> 6;
    const int l16  = lane & 15;
    const int g16  = lane >> 4;

    const short* WQ = wsb;
    const short* WK = wsb + 16384;
    const short* WV = wsb + 32768;
    const short* WC = wsb + 49152;

    // ---- weight fragments: held in registers across BOTH directions ----
    // wave owns output-cols [wid*32, wid*32+32) of each projection (nn = half)
    bf16x8 wqf[2][4], wkf[2][4], wvf[2][4];
    #pragma unroll
    for (int nn = 0; nn < 2; ++nn) {
        const int rw = ((wid * 2 + nn) * 16 + l16) * 128 + g16 * 8;
        #pragma unroll
        for (int k0 = 0; k0 < 4; ++k0) {
            wqf[nn][k0] = *(const bf16x8*)&WQ[rw + k0 * 32];
            wkf[nn][k0] = *(const bf16x8*)&WK[rw + k0 * 32];
            wvf[nn][k0] = *(const bf16x8*)&WV[rw + k0 * 32];
        }
    }
    bf16x8 wcf[2][2];   // [colbase-half][k0]: Wc rows wid*16+l16
    {
        const int rw = (wid * 16 + l16) * 128 + g16 * 8;
        #pragma unroll
        for (int cb = 0; cb < 2; ++cb)
            #pragma unroll
            for (int k0 = 0; k0 < 2; ++k0)
                wcf[cb][k0] = *(const bf16x8*)&WC[rw + cb * 64 + k0 * 32];
    }
    float bqv[2], bkv[2], bvv2[2];
    #pragma unroll
    for (int nn = 0; nn < 2; ++nn) {
        int sc_ = (wid * 2 + nn) * 16 + l16;
        bool ok = sc_ < SA;
        bqv[nn]  = ok ? bq[sc_] : 0.f;
        bkv[nn]  = ok ? bk[sc_] : 0.f;
        bvv2[nn] = ok ? bv[sc_] : 0.f;
    }

    // ---- stage lidar/hsi -> LDS bf16 (fragment layout, no div) + router row-sums ----
    {
        const int row = wid * 16 + l16;
        const float* gA = lidar + (size_t)b * 7744 + row * 121;
        const float* gB = hsi   + (size_t)b * 7744 + row * 121;
        float rsA = 0.f, rsB = 0.f;
        #pragma unroll
        for (int k0 = 0; k0 < 4; ++k0) {
            const int c0 = k0 * 32 + g16 * 8;
            bf16x8 a, h;
            if (c0 == 120) {                       // cols 120..127 (121..127 are K-pad = 0)
                float xa = gA[120], xb = gB[120];
                rsA += xa; rsB += xb;
                a[0] = f2bf(xa); h[0] = f2bf(xb);
                #pragma unroll
                for (int j = 1; j < 8; ++j) { a[j] = 0; h[j] = 0; }
            } else {
                #pragma unroll
                for (int j = 0; j < 8; ++j) {
                    float xa = gA[c0 + j], xb = gB[c0 + j];
                    rsA += xa; rsB += xb;
                    a[j] = f2bf(xa); h[j] = f2bf(xb);
                }
            }
            *(bf16x8*)&sA[row * 136 + c0] = a;
            *(bf16x8*)&sB[row * 136 + c0] = h;
        }
        rsA += __shfl_xor(rsA, 16, 64); rsA += __shfl_xor(rsA, 32, 64);
        rsB += __shfl_xor(rsB, 16, 64); rsB += __shfl_xor(rsB, 32, 64);
        if (g16 == 0) { sR[row] = rsA * (1.f / 121.f); sR[64 + row] = rsB * (1.f / 121.f); }
    }
    __syncthreads();   // bar0: staging visible to all waves

    f32x4 eacc[8];
    #pragma unroll
    for (int n = 0; n < 8; ++n) eacc[n] = (f32x4){0.f, 0.f, 0.f, 0.f};

    #pragma unroll 1
    for (int dir = 0; dir < 2; ++dir) {
        const short* Xqk = dir ? sB : sA;
        const short* Xv  = dir ? sA : sB;
        const int cb = dir ? 0 : 1;   // Wc col-half: dir0 -> cols 64:, dir1 -> cols :64

        // ========== phase A: q -> sC, k -> sD (wave owns out-cols, A from LDS) ========
        #pragma unroll 1
        for (int m = 0; m < 4; ++m) {
            bf16x8 afr[4];
            #pragma unroll
            for (int k0 = 0; k0 < 4; ++k0)
                afr[k0] = *(const bf16x8*)&Xqk[(m * 16 + l16) * 136 + k0 * 32 + g16 * 8];
            f32x4 qa[2], ka[2];
            qa[0] = (f32x4){0,0,0,0}; qa[1] = (f32x4){0,0,0,0};
            ka[0] = (f32x4){0,0,0,0}; ka[1] = (f32x4){0,0,0,0};
            #pragma unroll
            for (int k0 = 0; k0 < 4; ++k0)
                #pragma unroll
                for (int nn = 0; nn < 2; ++nn) {
                    qa[nn] = MFMA(afr[k0], wqf[nn][k0], qa[nn]);
                    ka[nn] = MFMA(afr[k0], wkf[nn][k0], ka[nn]);
                }
            #pragma unroll
            for (int nn = 0; nn < 2; ++nn) {
                int sc_ = (wid * 2 + nn) * 16 + l16;
                #pragma unroll
                for (int r = 0; r < 4; ++r) {
                    int row = m * 16 + g16 * 4 + r;
                    sC[row * 136 + sc_] = f2bf(qa[nn][r] + bqv[nn]);
                    sD[row * 136 + sc_] = f2bf(ka[nn][r] + bkv[nn]);
                }
            }
        }
        __syncthreads();   // bar1

        // ========== phase B: scores = q @ k^T, softmax, P^T -> sE =====================
        {
            f32x4 sc4[4];
            #pragma unroll
            for (int n = 0; n < 4; ++n) sc4[n] = (f32x4){0,0,0,0};
            #pragma unroll
            for (int k0 = 0; k0 < 4; ++k0) {
                bf16x8 afr = *(const bf16x8*)&sC[(wid * 16 + l16) * 136 + k0 * 32 + g16 * 8];
                #pragma unroll
                for (int n = 0; n < 4; ++n) {
                    bf16x8 bfr = *(const bf16x8*)&sD[(n * 16 + l16) * 136 + k0 * 32 + g16 * 8];
                    sc4[n] = MFMA(afr, bfr, sc4[n]);
                }
            }
            #pragma unroll
            for (int r = 0; r < 4; ++r) {
                float mx = fmaxf(fmaxf(sc4[0][r], sc4[1][r]), fmaxf(sc4[2][r], sc4[3][r]));
                #pragma unroll
                for (int off = 1; off < 16; off <<= 1) mx = fmaxf(mx, __shfl_xor(mx, off, 64));
                float e0 = exp2f((sc4[0][r] - mx) * 1.44269504f);
                float e1 = exp2f((sc4[1][r] - mx) * 1.44269504f);
                float e2 = exp2f((sc4[2][r] - mx) * 1.44269504f);
                float e3 = exp2f((sc4[3][r] - mx) * 1.44269504f);
                float sum = e0 + e1 + e2 + e3;
                #pragma unroll
                for (int off = 1; off < 16; off <<= 1) sum += __shfl_xor(sum, off, 64);
                float inv = 1.f / sum;
                int crow = wid * 16 + g16 * 4 + r;      // h row
                sE[(0 * 16 + l16) * 72 + crow] = f2bf(e0 * inv);
                sE[(1 * 16 + l16) * 72 + crow] = f2bf(e1 * inv);
                sE[(2 * 16 + l16) * 72 + crow] = f2bf(e2 * inv);
                sE[(3 * 16 + l16) * 72 + crow] = f2bf(e3 * inv);
            }
        }
        __syncthreads();   // bar2

        // ========== phase C: v-proj + gate -> G^T in sD; M = Wc_half @ P ==============
        {
            #pragma unroll 1
            for (int m = 0; m < 4; ++m) {
                bf16x8 afr[4];
                #pragma unroll
                for (int k0 = 0; k0 < 4; ++k0)
                    afr[k0] = *(const bf16x8*)&Xv[(m * 16 + l16) * 136 + k0 * 32 + g16 * 8];
                f32x4 va[2];
                va[0] = (f32x4){0,0,0,0}; va[1] = (f32x4){0,0,0,0};
                #pragma unroll
                for (int k0 = 0; k0 < 4; ++k0)
                    #pragma unroll
                    for (int nn = 0; nn < 2; ++nn)
                        va[nn] = MFMA(afr[k0], wvf[nn][k0], va[nn]);
                #pragma unroll
                for (int nn = 0; nn < 2; ++nn) {
                    int sc_ = (wid * 2 + nn) * 16 + l16;
                    #pragma unroll
                    for (int r = 0; r < 4; ++r) {
                        int c = m * 16 + g16 * 4 + r;
                        float qv = bf2f(sC[c * 136 + sc_]);   // own lane's q (same writer)
                        sD[sc_ * 72 + c] = f2bf((va[nn][r] + bvv2[nn]) * qv);   // G^T [s][c]
                    }
                }
            }
            // M = Wc[:, cb*64 : cb*64+64] @ P  (K = h; reads P^T in sE)
            f32x4 macc[4];
            #pragma unroll
            for (int n = 0; n < 4; ++n) macc[n] = (f32x4){0,0,0,0};
            #pragma unroll
            for (int k0 = 0; k0 < 2; ++k0)
                #pragma unroll
                for (int n = 0; n < 4; ++n) {
                    bf16x8 bfr = *(const bf16x8*)&sE[(n * 16 + l16) * 72 + k0 * 32 + g16 * 8];
                    macc[n] = MFMA(wcf[cb][k0], bfr, macc[n]);
                }
            __syncthreads();   // bar3: all P^T reads done before M overwrites sE
            #pragma unroll
            for (int n = 0; n < 4; ++n)
                #pragma unroll
                for (int r = 0; r < 4; ++r) {
                    int o = wid * 16 + g16 * 4 + r;
                    sE[o * 72 + n * 16 + l16] = f2bf(macc[n][r]);   // M [o][g]
                }
        }
        __syncthreads();   // bar4

        // ========== phase D: emb += M @ G =============================================
        #pragma unroll
        for (int k0 = 0; k0 < 2; ++k0) {
            bf16x8 afr = *(const bf16x8*)&sE[(wid * 16 + l16) * 72 + k0 * 32 + g16 * 8];
            #pragma unroll
            for (int n = 0; n < 8; ++n) {
                bf16x8 bfr = *(const bf16x8*)&sD[(n * 16 + l16) * 72 + k0 * 32 + g16 * 8];
                eacc[n] = MFMA(afr, bfr, eacc[n]);
            }
        }
        __syncthreads();   // bar5: protect sC/sD/sE for next dir
    }

    // ---- epilogue: emb + bc -> global ----
    float* eo = out + (size_t)b * 7744;
    {
        float bcv[4];
        #pragma unroll
        for (int r = 0; r < 4; ++r) bcv[r] = bc[wid * 16 + g16 * 4 + r];
        #pragma unroll
        for (int n = 0; n < 8; ++n) {
            int s = n * 16 + l16;
            if (s < SA) {
                #pragma unroll
                for (int r = 0; r < 4; ++r) {
                    int o = wid * 16 + g16 * 4 + r;
                    eo[o * 121 + s] = eacc[n][r] + bcv[r];
                }
            }
        }
    }

    // ---- router MLP (pooled means already in sR[0..127]) ----
    if (tid < 128) {
        float a0 = 0.f, a1 = 0.f, a2 = 0.f, a3 = 0.f;
        for (int c = 0; c < 128; c += 4) {
            a0 += sR[c]     * Wr1[(c)     * 128 + tid];
            a1 += sR[c + 1] * Wr1[(c + 1) * 128 + tid];
            a2 += sR[c + 2] * Wr1[(c + 2) * 128 + tid];
            a3 += sR[c + 3] * Wr1[(c + 3) * 128 + tid];
        }
        sR[128 + tid] = fmaxf((a0 + a1) + (a2 + a3) + br1[tid], 0.f);
    }
    __syncthreads();
    if (tid < 4) {
        float a0 = 0.f, a1 = 0.f, a2 = 0.f, a3 = 0.f;
        for (int h = 0; h < 128; h += 4) {
            a0 += sR[128 + h]     * Wr2[(h)     * 4 + tid];
            a1 += sR[128 + h + 1] * Wr2[(h + 1) * 4 + tid];
            a2 += sR[128 + h + 2] * Wr2[(h + 2) * 4 + tid];
            a3 += sR[128 + h + 3] * Wr2[(h + 3) * 4 + tid];
        }
        sR[256 + tid] = (a0 + a1) + (a2 + a3) + br2[tid];
    }
    __syncthreads();
    if (tid < 4) {
        float m = fmaxf(fmaxf(sR[256], sR[257]), fmaxf(sR[258], sR[259]));
        float e = __expf(sR[256 + tid] - m);
        float s = 0.f;
        for (int p = 0; p < 4; ++p) s += __expf(sR[256 + p] - m);
        out[EMB_TOTAL + b * 4 + tid] = e / s;
    }
}

extern "C" void kernel_launch(void* const* d_in, const int* in_sizes, int n_in,
                              void* d_out, int out_size, void* d_ws, size_t ws_size,
                              hipStream_t stream) {
    const float* lidar = (const float*)d_in[0];
    const float* hsi   = (const float*)d_in[1];
    const float* Wq  = (const float*)d_in[2];  const float* bq  = (const float*)d_in[3];
    const float* Wk  = (const float*)d_in[4];  const float* bk  = (const float*)d_in[5];
    const float* Wv  = (const float*)d_in[6];  const float* bv  = (const float*)d_in[7];
    const float* Wr1 = (const float*)d_in[8];  const float* br1 = (const float*)d_in[9];
    const float* Wr2 = (const float*)d_in[10]; const float* br2 = (const float*)d_in[11];
    const float* Wc  = (const float*)d_in[12]; const float* bc  = (const float*)d_in[13];
    short* wsb = (short*)d_ws;
    float* out = (float*)d_out;

    hipLaunchKernelGGL(convert_weights, dim3(224), dim3(256), 0, stream, Wq, Wk, Wv, Wc, wsb);
    hipLaunchKernelGGL(fused_kernel, dim3(NB), dim3(256), 0, stream,
                       lidar, hsi, bq, bk, bv, Wr1, br1, Wr2, br2, bc, wsb, out);
}